// Round 1
// baseline (208.705 us; speedup 1.0000x reference)
//
#include <hip/hip_runtime.h>
#include <math.h>

#define H 256

// ---------------------------------------------------------------------------
// Stage 1: scatter the 4 scalar weights per event into per-table-row bins.
//   W[r][c] = sum over events l with loc[l]==r of w_c(l)
// 2.6 MB of reads, 524K atomicAdds spread over 400K addresses (avg 1.31
// collisions per address) — far less contended than atomics on v.
// ---------------------------------------------------------------------------
__global__ __launch_bounds__(256) void strnn_scatter(
    const float* __restrict__ td_u, const float* __restrict__ td_l,
    const float* __restrict__ ld_u, const float* __restrict__ ld_l,
    const int* __restrict__ loc, float* __restrict__ W, int L)
{
    int i = blockIdx.x * blockDim.x + threadIdx.x;
    const int stride = gridDim.x * blockDim.x;
    for (; i < L; i += stride) {
        const float tu = fminf(fmaxf(td_u[i], 0.f), 1440.f);
        const float tl = fminf(fmaxf(td_l[i], 0.f), 1440.f);
        const float lu = fminf(fmaxf(ld_u[i], 0.f), 40.f);
        const float ll = fminf(fmaxf(ld_l[i], 0.f), 40.f);
        const float al = tu / (tu + tl);
        const float be = lu / (lu + ll);
        float* Wr = W + 4 * (size_t)loc[i];
        atomicAdd(Wr + 0, be * al);
        atomicAdd(Wr + 1, be * (1.f - al));
        atomicAdd(Wr + 2, (1.f - be) * al);
        atomicAdd(Wr + 3, (1.f - be) * (1.f - al));
    }
}

// ---------------------------------------------------------------------------
// Stage 2: v[c][h] = sum_r W[r][c] * table[r][h]  — SEQUENTIAL table stream.
// Each wave owns 8 consecutive rows per grid-stride step (8 KB contiguous);
// waves tile the table contiguously, so HBM sees a near-linear sweep (the
// access pattern the poison fills run at 6.5 TB/s). Rows whose weight quad
// is all-zero (~27% — never touched by any event) are skipped with a
// wave-uniform branch; the 8 row-loads of a group are issued before any
// FMA consumes them, preserving 8-deep MLP.
// ---------------------------------------------------------------------------
__global__ __launch_bounds__(512) void strnn_accum(
    const float* __restrict__ W, const float* __restrict__ table,
    float* __restrict__ v, int R)
{
    __shared__ float s_red[8][4][H];   // 32 KB: [wave][c][col]
    const int t    = threadIdx.x;
    const int wave = t >> 6;
    const int lane = t & 63;
    const int nwave = gridDim.x * 8;

    float4 a0 = {0,0,0,0}, a1 = {0,0,0,0}, a2 = {0,0,0,0}, a3 = {0,0,0,0};

    for (int r0 = (blockIdx.x * 8 + wave) * 8; r0 < R; r0 += nwave * 8) {
        float4 wv[8], e[8];
        #pragma unroll
        for (int u = 0; u < 8; ++u) {
            const int r = r0 + u;
            wv[u] = (r < R) ? *(const float4*)(W + 4 * (size_t)r)
                            : make_float4(0.f, 0.f, 0.f, 0.f);
        }
        #pragma unroll
        for (int u = 0; u < 8; ++u) {
            e[u] = make_float4(0.f, 0.f, 0.f, 0.f);
            const float4 w = wv[u];
            if (w.x != 0.f || w.y != 0.f || w.z != 0.f || w.w != 0.f)
                e[u] = *(const float4*)(table + (size_t)(r0 + u) * H + 4 * lane);
        }
        #pragma unroll
        for (int u = 0; u < 8; ++u) {
            const float4 w = wv[u];
            a0.x = fmaf(w.x, e[u].x, a0.x);
            a0.y = fmaf(w.x, e[u].y, a0.y);
            a0.z = fmaf(w.x, e[u].z, a0.z);
            a0.w = fmaf(w.x, e[u].w, a0.w);
            a1.x = fmaf(w.y, e[u].x, a1.x);
            a1.y = fmaf(w.y, e[u].y, a1.y);
            a1.z = fmaf(w.y, e[u].z, a1.z);
            a1.w = fmaf(w.y, e[u].w, a1.w);
            a2.x = fmaf(w.z, e[u].x, a2.x);
            a2.y = fmaf(w.z, e[u].y, a2.y);
            a2.z = fmaf(w.z, e[u].z, a2.z);
            a2.w = fmaf(w.z, e[u].w, a2.w);
            a3.x = fmaf(w.w, e[u].x, a3.x);
            a3.y = fmaf(w.w, e[u].y, a3.y);
            a3.z = fmaf(w.w, e[u].z, a3.z);
            a3.w = fmaf(w.w, e[u].w, a3.w);
        }
    }

    // cross-wave block reduction in LDS (8 waves)
    *(float4*)&s_red[wave][0][4 * lane] = a0;
    *(float4*)&s_red[wave][1][4 * lane] = a1;
    *(float4*)&s_red[wave][2][4 * lane] = a2;
    *(float4*)&s_red[wave][3][4 * lane] = a3;
    __syncthreads();
    const int col = t & 255;
    #pragma unroll
    for (int cc = 0; cc < 2; ++cc) {
        const int c = (t >> 8) * 2 + cc;
        float s = 0.f;
        #pragma unroll
        for (int wv_ = 0; wv_ < 8; ++wv_)
            s += s_red[wv_][c][col];
        atomicAdd(&v[c * H + col], s);
    }
}

// Kernel 3: one wave per output row h:
//   p[h] = Wtu[h,:]·v1 + Wtl[h,:]·v2
//   q[h] = Wtu[h,:]·v3 + Wtl[h,:]·v4
//   u[h] = Wih[h,:]·hx
__global__ __launch_bounds__(256) void strnn_mid(
    const float* __restrict__ Wtu, const float* __restrict__ Wtl,
    const float* __restrict__ Wih, const float* __restrict__ hx,
    const float* __restrict__ v, float* __restrict__ pqu)
{
    const int wave = (blockIdx.x * blockDim.x + threadIdx.x) >> 6;  // = h
    const int lane = threadIdx.x & 63;
    const float* v1 = v;
    const float* v2 = v + H;
    const float* v3 = v + 2 * H;
    const float* v4 = v + 3 * H;

    float p = 0.f, q = 0.f, u = 0.f;
    #pragma unroll
    for (int i = 0; i < H; i += 64) {
        const int k = i + lane;
        const float wtu = Wtu[wave * H + k];
        const float wtl = Wtl[wave * H + k];
        p = fmaf(wtu, v1[k], fmaf(wtl, v2[k], p));
        q = fmaf(wtu, v3[k], fmaf(wtl, v4[k], q));
        u = fmaf(Wih[wave * H + k], hx[k], u);
    }
    #pragma unroll
    for (int off = 32; off > 0; off >>= 1) {
        p += __shfl_down(p, off, 64);
        q += __shfl_down(q, off, 64);
        u += __shfl_down(u, off, 64);
    }
    if (lane == 0) {
        pqu[wave]         = p;
        pqu[H + wave]     = q;
        pqu[2 * H + wave] = u;
    }
}

// Kernel 4: out[h] = sigmoid( Wsu[h,:]·p + Wsl[h,:]·q + u[h] )
__global__ __launch_bounds__(256) void strnn_out(
    const float* __restrict__ Wsu, const float* __restrict__ Wsl,
    const float* __restrict__ pqu, float* __restrict__ out)
{
    const int wave = (blockIdx.x * blockDim.x + threadIdx.x) >> 6;  // = h
    const int lane = threadIdx.x & 63;
    const float* p = pqu;
    const float* q = pqu + H;
    const float* u = pqu + 2 * H;

    float s = 0.f;
    #pragma unroll
    for (int i = 0; i < H; i += 64) {
        const int k = i + lane;
        s = fmaf(Wsu[wave * H + k], p[k], fmaf(Wsl[wave * H + k], q[k], s));
    }
    #pragma unroll
    for (int off = 32; off > 0; off >>= 1)
        s += __shfl_down(s, off, 64);
    if (lane == 0)
        out[wave] = 1.f / (1.f + expf(-(s + u[wave])));
}

extern "C" void kernel_launch(void* const* d_in, const int* in_sizes, int n_in,
                              void* d_out, int out_size, void* d_ws, size_t ws_size,
                              hipStream_t stream) {
    const float* td_u  = (const float*)d_in[0];
    const float* td_l  = (const float*)d_in[1];
    const float* ld_u  = (const float*)d_in[2];
    const float* ld_l  = (const float*)d_in[3];
    const int*   loc   = (const int*)d_in[4];
    const float* hx    = (const float*)d_in[5];
    const float* Wih   = (const float*)d_in[6];
    const float* Wtu   = (const float*)d_in[7];
    const float* Wtl   = (const float*)d_in[8];
    const float* Wsu   = (const float*)d_in[9];
    const float* Wsl   = (const float*)d_in[10];
    const float* table = (const float*)d_in[11];
    const int L = in_sizes[0];
    const int R = in_sizes[11] / H;     // table rows (LOC_CNT)

    float* W   = (float*)d_ws;          // R*4 per-row weight bins
    float* v   = W + (size_t)R * 4;     // 4*H accumulators
    float* pqu = v + 4 * H;             // p, q, usr (3*H)

    // ws is re-poisoned to 0xAA before every launch — zero W bins + v.
    hipMemsetAsync(W, 0, ((size_t)R * 4 + 4 * H) * sizeof(float), stream);

    strnn_scatter<<<512, 256, 0, stream>>>(td_u, td_l, ld_u, ld_l, loc, W, L);
    strnn_accum<<<512, 512, 0, stream>>>(W, table, v, R);
    strnn_mid<<<64, 256, 0, stream>>>(Wtu, Wtl, Wih, hx, v, pqu);
    strnn_out<<<64, 256, 0, stream>>>(Wsu, Wsl, pqu, (float*)d_out);
}

// Round 2
// 203.513 us; speedup vs baseline: 1.0255x; 1.0255x over previous
//
#include <hip/hip_runtime.h>
#include <math.h>

#define H 256

// ---------------------------------------------------------------------------
// Stage 1: scatter the 4 scalar weights per event into PLANAR per-row bins:
//   Wc[r] = sum over events l with loc[l]==r of w_c(l),  c = 0..3
// Planes are Rpad apart, so one thread's 4 atomics hit 4 different cache
// lines (4 different L2 slices) instead of serializing on one line.
// Atomics are fire-and-forget (no return value) -> pipelined.
// ---------------------------------------------------------------------------
__global__ __launch_bounds__(256) void strnn_scatter(
    const float* __restrict__ td_u, const float* __restrict__ td_l,
    const float* __restrict__ ld_u, const float* __restrict__ ld_l,
    const int* __restrict__ loc, float* __restrict__ W, int L, int Rpad)
{
    const int i = blockIdx.x * blockDim.x + threadIdx.x;
    if (i >= L) return;
    const float tu = fminf(fmaxf(td_u[i], 0.f), 1440.f);
    const float tl = fminf(fmaxf(td_l[i], 0.f), 1440.f);
    const float lu = fminf(fmaxf(ld_u[i], 0.f), 40.f);
    const float ll = fminf(fmaxf(ld_l[i], 0.f), 40.f);
    const float al = tu / (tu + tl);
    const float be = lu / (lu + ll);
    const int r = loc[i];
    atomicAdd(W + r,            be * al);
    atomicAdd(W + Rpad + r,     be * (1.f - al));
    atomicAdd(W + 2 * Rpad + r, (1.f - be) * al);
    atomicAdd(W + 3 * Rpad + r, (1.f - be) * (1.f - al));
}

// ---------------------------------------------------------------------------
// Stage 2: v[c][h] = sum_r Wc[r] * table[r][h]  — SEQUENTIAL table stream.
// 512-thread blocks, 8 waves each; wave owns 8 consecutive rows per step
// (8 KB contiguous), block covers 64 KB contiguous. BRANCHLESS zero-row
// skip: rows with all-zero weight quad redirect the load address to row 0
// (cndmask on the address). Row 0 stays L1-resident, so skipped rows cost
// ~nothing while the 8-deep load batch stays intact (no branches between
// the 8 global_loads). FMA with w==0 keeps the result exact.
// ---------------------------------------------------------------------------
__global__ __launch_bounds__(512) void strnn_accum(
    const float* __restrict__ W, const float* __restrict__ table,
    float* __restrict__ v, int R, int Rpad)
{
    __shared__ float s_red[8][4][H];   // 32 KB
    const int t    = threadIdx.x;
    const int wave = t >> 6;
    const int lane = t & 63;
    const float* __restrict__ W0 = W;
    const float* __restrict__ W1 = W + Rpad;
    const float* __restrict__ W2 = W + 2 * (size_t)Rpad;
    const float* __restrict__ W3 = W + 3 * (size_t)Rpad;

    float4 a0 = {0,0,0,0}, a1 = {0,0,0,0}, a2 = {0,0,0,0}, a3 = {0,0,0,0};

    const int gw     = blockIdx.x * 8 + wave;     // global wave id
    const int stride = gridDim.x * 8 * 8;         // rows per sweep

    for (int r0 = gw * 8; r0 < R; r0 += stride) {
        // broadcast weight rows: 8 x 16B same-address loads (padded planes,
        // pad entries are zero -> behave as skipped rows)
        float w0[8], w1[8], w2[8], w3[8];
        *(float4*)&w0[0] = *(const float4*)(W0 + r0);
        *(float4*)&w0[4] = *(const float4*)(W0 + r0 + 4);
        *(float4*)&w1[0] = *(const float4*)(W1 + r0);
        *(float4*)&w1[4] = *(const float4*)(W1 + r0 + 4);
        *(float4*)&w2[0] = *(const float4*)(W2 + r0);
        *(float4*)&w2[4] = *(const float4*)(W2 + r0 + 4);
        *(float4*)&w3[0] = *(const float4*)(W3 + r0);
        *(float4*)&w3[4] = *(const float4*)(W3 + r0 + 4);

        float4 e[8];
        #pragma unroll
        for (int u = 0; u < 8; ++u) {
            const int r = r0 + u;
            const bool live = (r < R) &&
                (w0[u] != 0.f || w1[u] != 0.f || w2[u] != 0.f || w3[u] != 0.f);
            const size_t roff = live ? (size_t)r * H : (size_t)0;
            e[u] = *(const float4*)(table + roff + 4 * lane);  // 8 in flight
        }
        #pragma unroll
        for (int u = 0; u < 8; ++u) {
            a0.x = fmaf(w0[u], e[u].x, a0.x);
            a0.y = fmaf(w0[u], e[u].y, a0.y);
            a0.z = fmaf(w0[u], e[u].z, a0.z);
            a0.w = fmaf(w0[u], e[u].w, a0.w);
            a1.x = fmaf(w1[u], e[u].x, a1.x);
            a1.y = fmaf(w1[u], e[u].y, a1.y);
            a1.z = fmaf(w1[u], e[u].z, a1.z);
            a1.w = fmaf(w1[u], e[u].w, a1.w);
            a2.x = fmaf(w2[u], e[u].x, a2.x);
            a2.y = fmaf(w2[u], e[u].y, a2.y);
            a2.z = fmaf(w2[u], e[u].z, a2.z);
            a2.w = fmaf(w2[u], e[u].w, a2.w);
            a3.x = fmaf(w3[u], e[u].x, a3.x);
            a3.y = fmaf(w3[u], e[u].y, a3.y);
            a3.z = fmaf(w3[u], e[u].z, a3.z);
            a3.w = fmaf(w3[u], e[u].w, a3.w);
        }
    }

    // cross-wave block reduction in LDS (8 waves), then 256-per-address
    // atomic tail onto v (64 lines in parallel across L2 slices, ~3 us).
    *(float4*)&s_red[wave][0][4 * lane] = a0;
    *(float4*)&s_red[wave][1][4 * lane] = a1;
    *(float4*)&s_red[wave][2][4 * lane] = a2;
    *(float4*)&s_red[wave][3][4 * lane] = a3;
    __syncthreads();
    const int col = t & 255;
    #pragma unroll
    for (int cc = 0; cc < 2; ++cc) {
        const int c = (t >> 8) * 2 + cc;
        float s = 0.f;
        #pragma unroll
        for (int w_ = 0; w_ < 8; ++w_)
            s += s_red[w_][c][col];
        atomicAdd(&v[c * H + col], s);
    }
}

// Kernel 3: one wave per output row h:
//   p[h] = Wtu[h,:]·v1 + Wtl[h,:]·v2
//   q[h] = Wtu[h,:]·v3 + Wtl[h,:]·v4
//   u[h] = Wih[h,:]·hx
__global__ __launch_bounds__(256) void strnn_mid(
    const float* __restrict__ Wtu, const float* __restrict__ Wtl,
    const float* __restrict__ Wih, const float* __restrict__ hx,
    const float* __restrict__ v, float* __restrict__ pqu)
{
    const int wave = (blockIdx.x * blockDim.x + threadIdx.x) >> 6;  // = h
    const int lane = threadIdx.x & 63;
    const float* v1 = v;
    const float* v2 = v + H;
    const float* v3 = v + 2 * H;
    const float* v4 = v + 3 * H;

    float p = 0.f, q = 0.f, u = 0.f;
    #pragma unroll
    for (int i = 0; i < H; i += 64) {
        const int k = i + lane;
        const float wtu = Wtu[wave * H + k];
        const float wtl = Wtl[wave * H + k];
        p = fmaf(wtu, v1[k], fmaf(wtl, v2[k], p));
        q = fmaf(wtu, v3[k], fmaf(wtl, v4[k], q));
        u = fmaf(Wih[wave * H + k], hx[k], u);
    }
    #pragma unroll
    for (int off = 32; off > 0; off >>= 1) {
        p += __shfl_down(p, off, 64);
        q += __shfl_down(q, off, 64);
        u += __shfl_down(u, off, 64);
    }
    if (lane == 0) {
        pqu[wave]         = p;
        pqu[H + wave]     = q;
        pqu[2 * H + wave] = u;
    }
}

// Kernel 4: out[h] = sigmoid( Wsu[h,:]·p + Wsl[h,:]·q + u[h] )
__global__ __launch_bounds__(256) void strnn_out(
    const float* __restrict__ Wsu, const float* __restrict__ Wsl,
    const float* __restrict__ pqu, float* __restrict__ out)
{
    const int wave = (blockIdx.x * blockDim.x + threadIdx.x) >> 6;  // = h
    const int lane = threadIdx.x & 63;
    const float* p = pqu;
    const float* q = pqu + H;
    const float* u = pqu + 2 * H;

    float s = 0.f;
    #pragma unroll
    for (int i = 0; i < H; i += 64) {
        const int k = i + lane;
        s = fmaf(Wsu[wave * H + k], p[k], fmaf(Wsl[wave * H + k], q[k], s));
    }
    #pragma unroll
    for (int off = 32; off > 0; off >>= 1)
        s += __shfl_down(s, off, 64);
    if (lane == 0)
        out[wave] = 1.f / (1.f + expf(-(s + u[wave])));
}

extern "C" void kernel_launch(void* const* d_in, const int* in_sizes, int n_in,
                              void* d_out, int out_size, void* d_ws, size_t ws_size,
                              hipStream_t stream) {
    const float* td_u  = (const float*)d_in[0];
    const float* td_l  = (const float*)d_in[1];
    const float* ld_u  = (const float*)d_in[2];
    const float* ld_l  = (const float*)d_in[3];
    const int*   loc   = (const int*)d_in[4];
    const float* hx    = (const float*)d_in[5];
    const float* Wih   = (const float*)d_in[6];
    const float* Wtu   = (const float*)d_in[7];
    const float* Wtl   = (const float*)d_in[8];
    const float* Wsu   = (const float*)d_in[9];
    const float* Wsl   = (const float*)d_in[10];
    const float* table = (const float*)d_in[11];
    const int L = in_sizes[0];
    const int R = in_sizes[11] / H;          // table rows (LOC_CNT)
    const int Rpad = (R + 7) & ~7;           // 16B-aligned planes, zero pad

    float* W   = (float*)d_ws;               // 4 planar weight planes
    float* v   = W + 4 * (size_t)Rpad;       // 4*H accumulators
    float* pqu = v + 4 * H;                  // p, q, usr (3*H)

    // ws is re-poisoned to 0xAA before every launch — zero W planes + v.
    hipMemsetAsync(W, 0, (4 * (size_t)Rpad + 4 * H) * sizeof(float), stream);

    strnn_scatter<<<(L + 255) / 256, 256, 0, stream>>>(
        td_u, td_l, ld_u, ld_l, loc, W, L, Rpad);
    strnn_accum<<<256, 512, 0, stream>>>(W, table, v, R, Rpad);
    strnn_mid<<<64, 256, 0, stream>>>(Wtu, Wtl, Wih, hx, v, pqu);
    strnn_out<<<64, 256, 0, stream>>>(Wsu, Wsl, pqu, (float*)d_out);
}

// Round 3
// 197.403 us; speedup vs baseline: 1.0573x; 1.0309x over previous
//
#include <hip/hip_runtime.h>
#include <math.h>

#define H 256
typedef unsigned long long u64;

// ---------------------------------------------------------------------------
// Stage 1: scatter per-event weight components into per-row fixed-point bins.
// ONE u64 atomic carries two 32-bit fixed-point sums (2^-24 quantization):
//   U1[r] += (al_q << 32) | be_q
//   U2[r] += (ab_q << 32) | 1          (ab = al*be; low half counts events)
// Max ~15 events/row -> each half stays < 2^28: no cross-half carry.
// 2 atomics/event instead of 4 — tests the atomic-throughput hypothesis.
// ---------------------------------------------------------------------------
__global__ __launch_bounds__(256) void strnn_scatter(
    const float* __restrict__ td_u, const float* __restrict__ td_l,
    const float* __restrict__ ld_u, const float* __restrict__ ld_l,
    const int* __restrict__ loc, u64* __restrict__ U1, u64* __restrict__ U2,
    int L)
{
    const int i = blockIdx.x * blockDim.x + threadIdx.x;
    if (i >= L) return;
    const float tu = fminf(fmaxf(td_u[i], 0.f), 1440.f);
    const float tl = fminf(fmaxf(td_l[i], 0.f), 1440.f);
    const float lu = fminf(fmaxf(ld_u[i], 0.f), 40.f);
    const float ll = fminf(fmaxf(ld_l[i], 0.f), 40.f);
    const float al = tu / (tu + tl);
    const float be = lu / (lu + ll);
    const u64 alq = (u64)(unsigned)(al * 16777216.f + 0.5f);
    const u64 beq = (u64)(unsigned)(be * 16777216.f + 0.5f);
    const u64 abq = (u64)(unsigned)(al * be * 16777216.f + 0.5f);
    const int r = loc[i];
    atomicAdd(U1 + r, (alq << 32) | beq);
    atomicAdd(U2 + r, (abq << 32) | 1ull);
}

// ---------------------------------------------------------------------------
// Stage 2: v[c][h] = sum_r Wc(r) * table[r][h] — UNCONDITIONAL sequential
// table stream. Table-load addresses depend only on the induction variable
// (no cndmask on loaded data), so the 8 row-loads of a group issue
// immediately and overlap the U-plane broadcast loads — the round-2
// W->table serial chain is gone. Weights are derived per row from the
// fixed-point sums; rows never hit by an event decode to all-zero weights
// and contribute exactly 0.
// ---------------------------------------------------------------------------
__global__ __launch_bounds__(512, 4) void strnn_accum(
    const u64* __restrict__ U1, const u64* __restrict__ U2,
    const float* __restrict__ table, float* __restrict__ v, int R)
{
    __shared__ float s_red[8][4][H];   // 32 KB
    const int t    = threadIdx.x;
    const int wave = t >> 6;
    const int lane = t & 63;

    float4 a0 = {0,0,0,0}, a1 = {0,0,0,0}, a2 = {0,0,0,0}, a3 = {0,0,0,0};

    const int gw     = blockIdx.x * 8 + wave;   // global wave id
    const int stride = gridDim.x * 8 * 8;       // rows per sweep (512*64)

    for (int r0 = gw * 8; r0 < R; r0 += stride) {
        // broadcast fixed-point weight rows: 8 x 16B loads (2 rows each)
        uint4 q1[4], q2[4];
        #pragma unroll
        for (int k = 0; k < 4; ++k) {
            q1[k] = *(const uint4*)(U1 + r0 + 2 * k);
            q2[k] = *(const uint4*)(U2 + r0 + 2 * k);
        }
        // 8 independent 1KB row loads, issued back-to-back
        float4 e[8];
        #pragma unroll
        for (int u = 0; u < 8; ++u) {
            int r = r0 + u;
            r = (r < R) ? r : (R - 1);          // tail clamp (R%8==0: never)
            e[u] = *(const float4*)(table + (size_t)r * H + 4 * lane);
        }
        const float S = 5.9604644775390625e-8f; // 2^-24
        #pragma unroll
        for (int u = 0; u < 8; ++u) {
            const uint4 q = q1[u >> 1];
            const uint4 p = q2[u >> 1];
            const float be_s = (float)((u & 1) ? q.z : q.x) * S;
            const float al_s = (float)((u & 1) ? q.w : q.y) * S;
            const float ab   = (float)((u & 1) ? p.w : p.y) * S;
            const float n    = (float)((u & 1) ? p.z : p.x);
            const float w0 = ab;
            const float w1 = be_s - ab;
            const float w2 = al_s - ab;
            const float w3 = n - al_s - be_s + ab;
            a0.x = fmaf(w0, e[u].x, a0.x);
            a0.y = fmaf(w0, e[u].y, a0.y);
            a0.z = fmaf(w0, e[u].z, a0.z);
            a0.w = fmaf(w0, e[u].w, a0.w);
            a1.x = fmaf(w1, e[u].x, a1.x);
            a1.y = fmaf(w1, e[u].y, a1.y);
            a1.z = fmaf(w1, e[u].z, a1.z);
            a1.w = fmaf(w1, e[u].w, a1.w);
            a2.x = fmaf(w2, e[u].x, a2.x);
            a2.y = fmaf(w2, e[u].y, a2.y);
            a2.z = fmaf(w2, e[u].z, a2.z);
            a2.w = fmaf(w2, e[u].w, a2.w);
            a3.x = fmaf(w3, e[u].x, a3.x);
            a3.y = fmaf(w3, e[u].y, a3.y);
            a3.z = fmaf(w3, e[u].z, a3.z);
            a3.w = fmaf(w3, e[u].w, a3.w);
        }
    }

    // cross-wave block reduction in LDS (8 waves), then 512-per-address
    // atomic tail onto v (64 lines in parallel across slices)
    *(float4*)&s_red[wave][0][4 * lane] = a0;
    *(float4*)&s_red[wave][1][4 * lane] = a1;
    *(float4*)&s_red[wave][2][4 * lane] = a2;
    *(float4*)&s_red[wave][3][4 * lane] = a3;
    __syncthreads();
    const int col = t & 255;
    #pragma unroll
    for (int cc = 0; cc < 2; ++cc) {
        const int c = (t >> 8) * 2 + cc;
        float s = 0.f;
        #pragma unroll
        for (int w_ = 0; w_ < 8; ++w_)
            s += s_red[w_][c][col];
        atomicAdd(&v[c * H + col], s);
    }
}

// Kernel 3: one wave per output row h:
//   p[h] = Wtu[h,:]·v1 + Wtl[h,:]·v2
//   q[h] = Wtu[h,:]·v3 + Wtl[h,:]·v4
//   u[h] = Wih[h,:]·hx
__global__ __launch_bounds__(256) void strnn_mid(
    const float* __restrict__ Wtu, const float* __restrict__ Wtl,
    const float* __restrict__ Wih, const float* __restrict__ hx,
    const float* __restrict__ v, float* __restrict__ pqu)
{
    const int wave = (blockIdx.x * blockDim.x + threadIdx.x) >> 6;  // = h
    const int lane = threadIdx.x & 63;
    const float* v1 = v;
    const float* v2 = v + H;
    const float* v3 = v + 2 * H;
    const float* v4 = v + 3 * H;

    float p = 0.f, q = 0.f, u = 0.f;
    #pragma unroll
    for (int i = 0; i < H; i += 64) {
        const int k = i + lane;
        const float wtu = Wtu[wave * H + k];
        const float wtl = Wtl[wave * H + k];
        p = fmaf(wtu, v1[k], fmaf(wtl, v2[k], p));
        q = fmaf(wtu, v3[k], fmaf(wtl, v4[k], q));
        u = fmaf(Wih[wave * H + k], hx[k], u);
    }
    #pragma unroll
    for (int off = 32; off > 0; off >>= 1) {
        p += __shfl_down(p, off, 64);
        q += __shfl_down(q, off, 64);
        u += __shfl_down(u, off, 64);
    }
    if (lane == 0) {
        pqu[wave]         = p;
        pqu[H + wave]     = q;
        pqu[2 * H + wave] = u;
    }
}

// Kernel 4: out[h] = sigmoid( Wsu[h,:]·p + Wsl[h,:]·q + u[h] )
__global__ __launch_bounds__(256) void strnn_out(
    const float* __restrict__ Wsu, const float* __restrict__ Wsl,
    const float* __restrict__ pqu, float* __restrict__ out)
{
    const int wave = (blockIdx.x * blockDim.x + threadIdx.x) >> 6;  // = h
    const int lane = threadIdx.x & 63;
    const float* p = pqu;
    const float* q = pqu + H;
    const float* u = pqu + 2 * H;

    float s = 0.f;
    #pragma unroll
    for (int i = 0; i < H; i += 64) {
        const int k = i + lane;
        s = fmaf(Wsu[wave * H + k], p[k], fmaf(Wsl[wave * H + k], q[k], s));
    }
    #pragma unroll
    for (int off = 32; off > 0; off >>= 1)
        s += __shfl_down(s, off, 64);
    if (lane == 0)
        out[wave] = 1.f / (1.f + expf(-(s + u[wave])));
}

extern "C" void kernel_launch(void* const* d_in, const int* in_sizes, int n_in,
                              void* d_out, int out_size, void* d_ws, size_t ws_size,
                              hipStream_t stream) {
    const float* td_u  = (const float*)d_in[0];
    const float* td_l  = (const float*)d_in[1];
    const float* ld_u  = (const float*)d_in[2];
    const float* ld_l  = (const float*)d_in[3];
    const int*   loc   = (const int*)d_in[4];
    const float* hx    = (const float*)d_in[5];
    const float* Wih   = (const float*)d_in[6];
    const float* Wtu   = (const float*)d_in[7];
    const float* Wtl   = (const float*)d_in[8];
    const float* Wsu   = (const float*)d_in[9];
    const float* Wsl   = (const float*)d_in[10];
    const float* table = (const float*)d_in[11];
    const int L = in_sizes[0];
    const int R = in_sizes[11] / H;          // table rows (LOC_CNT)
    const int Rpad = (R + 7) & ~7;           // group-of-8 aligned, zero pad

    u64*   U1  = (u64*)d_ws;                 // Σal | Σbe  fixed-point plane
    u64*   U2  = U1 + Rpad;                  // Σ(al·be) | count plane
    float* v   = (float*)(U2 + Rpad);        // 4*H accumulators
    float* pqu = v + 4 * H;                  // p, q, usr (3*H)

    // ws is re-poisoned to 0xAA before every launch — zero U planes + v.
    hipMemsetAsync(U1, 0, 2 * (size_t)Rpad * sizeof(u64) + 4 * H * sizeof(float),
                   stream);

    strnn_scatter<<<(L + 255) / 256, 256, 0, stream>>>(
        td_u, td_l, ld_u, ld_l, loc, U1, U2, L);
    strnn_accum<<<512, 512, 0, stream>>>(U1, U2, table, v, R);
    strnn_mid<<<64, 256, 0, stream>>>(Wtu, Wtl, Wih, hx, v, pqu);
    strnn_out<<<64, 256, 0, stream>>>(Wsu, Wsl, pqu, (float*)d_out);
}

// Round 4
// 189.491 us; speedup vs baseline: 1.1014x; 1.0418x over previous
//
#include <hip/hip_runtime.h>
#include <math.h>

#define H 256
#define TILE 256
#define NBLK 512   // gather grid = partial slots
#define NMID 64    // midout grid (co-resident on 256 CUs -> spin barrier safe)

// ---------------------------------------------------------------------------
// ws layout (floats):
//   [0 .. 63]      header: two unsigned barrier counters at byte 0 and 128
//   [64 .. 1087]   v[4][H]        (reduced accumulators)
//   [1088 .. 1855] pqu[3][H]      (p, q, usr)
//   [2048 .. ]     part[NBLK][4][H]   (per-block partials, 2 MB)
// No memset: part is fully overwritten; counters zeroed by gather (visible
// to midout via the kernel-boundary fence of stream ordering).
// ---------------------------------------------------------------------------

// Kernel 1: v-partials via gather. Wave w owns 64 rows of the block's
// 256-event tile; one global_load_dwordx4 per lane covers a full 1 KB table
// row per wave instruction; 8 rows in flight (8 KB/wave). Weights broadcast
// from LDS as float4. Cross-wave LDS reduction, then each block stores its
// private 4x256 partial — NO atomics, no contention.
__global__ __launch_bounds__(256) void strnn_gather(
    const float* __restrict__ td_u, const float* __restrict__ td_l,
    const float* __restrict__ ld_u, const float* __restrict__ ld_l,
    const int* __restrict__ loc, const float* __restrict__ table,
    unsigned* __restrict__ hdr, float* __restrict__ part, int L)
{
    __shared__ float4 s_w[TILE];       //  4 KB
    __shared__ int    s_loc[TILE];     //  1 KB
    __shared__ float  s_red[4][4][H];  // 16 KB: [wave][c][col]
    const int t    = threadIdx.x;
    const int wave = t >> 6;
    const int lane = t & 63;

    if (blockIdx.x == 0 && t < 64) hdr[t] = 0u;  // zero both counters

    float4 a0 = {0,0,0,0}, a1 = {0,0,0,0}, a2 = {0,0,0,0}, a3 = {0,0,0,0};

    for (int base = blockIdx.x * TILE; base < L; base += gridDim.x * TILE) {
        const int l = base + t;
        const bool ok = (l < L);
        float tu = ok ? fminf(fmaxf(td_u[l], 0.f), 1440.f) : 1.f;
        float tl = ok ? fminf(fmaxf(td_l[l], 0.f), 1440.f) : 1.f;
        float lu = ok ? fminf(fmaxf(ld_u[l], 0.f), 40.f)   : 1.f;
        float ll = ok ? fminf(fmaxf(ld_l[l], 0.f), 40.f)   : 1.f;
        float al = tu / (tu + tl);
        float be = lu / (lu + ll);
        float w0 = be * al, w1 = be * (1.f - al);
        float w2 = (1.f - be) * al, w3 = (1.f - be) * (1.f - al);
        if (!ok) { w0 = w1 = w2 = w3 = 0.f; }
        s_w[t]   = make_float4(w0, w1, w2, w3);
        s_loc[t] = ok ? loc[l] : 0;
        __syncthreads();

        const int r0 = wave * 64;
        #pragma unroll 2
        for (int j = 0; j < 64; j += 8) {
            const float4* addr[8];
            #pragma unroll
            for (int u = 0; u < 8; ++u)
                addr[u] = (const float4*)(table + (size_t)s_loc[r0 + j + u] * H + 4 * lane);
            float4 w[8], e[8];
            #pragma unroll
            for (int u = 0; u < 8; ++u)
                e[u] = *addr[u];                 // 8 loads in flight
            #pragma unroll
            for (int u = 0; u < 8; ++u)
                w[u] = s_w[r0 + j + u];          // broadcast ds_read_b128
            #pragma unroll
            for (int u = 0; u < 8; ++u) {
                a0.x = fmaf(w[u].x, e[u].x, a0.x);
                a0.y = fmaf(w[u].x, e[u].y, a0.y);
                a0.z = fmaf(w[u].x, e[u].z, a0.z);
                a0.w = fmaf(w[u].x, e[u].w, a0.w);
                a1.x = fmaf(w[u].y, e[u].x, a1.x);
                a1.y = fmaf(w[u].y, e[u].y, a1.y);
                a1.z = fmaf(w[u].y, e[u].z, a1.z);
                a1.w = fmaf(w[u].y, e[u].w, a1.w);
                a2.x = fmaf(w[u].z, e[u].x, a2.x);
                a2.y = fmaf(w[u].z, e[u].y, a2.y);
                a2.z = fmaf(w[u].z, e[u].z, a2.z);
                a2.w = fmaf(w[u].z, e[u].w, a2.w);
                a3.x = fmaf(w[u].w, e[u].x, a3.x);
                a3.y = fmaf(w[u].w, e[u].y, a3.y);
                a3.z = fmaf(w[u].w, e[u].z, a3.z);
                a3.w = fmaf(w[u].w, e[u].w, a3.w);
            }
        }
        __syncthreads();
    }

    // cross-wave block reduction in LDS, then plain coalesced partial store
    *(float4*)&s_red[wave][0][4 * lane] = a0;
    *(float4*)&s_red[wave][1][4 * lane] = a1;
    *(float4*)&s_red[wave][2][4 * lane] = a2;
    *(float4*)&s_red[wave][3][4 * lane] = a3;
    __syncthreads();
    float* pb = part + (size_t)blockIdx.x * 4 * H;
    #pragma unroll
    for (int c = 0; c < 4; ++c) {
        float s = s_red[0][c][t] + s_red[1][c][t] + s_red[2][c][t] + s_red[3][c][t];
        pb[c * H + t] = s;
    }
}

// Kernel 2 (fused): reduce partials -> v, device barrier, mid GEMV -> pqu,
// device barrier, out GEMV -> sigmoid. 64 blocks (all co-resident).
__global__ __launch_bounds__(256) void strnn_midout(
    const float* __restrict__ Wtu, const float* __restrict__ Wtl,
    const float* __restrict__ Wih, const float* __restrict__ Wsu,
    const float* __restrict__ Wsl, const float* __restrict__ hx,
    const float* __restrict__ part, float* __restrict__ v,
    float* __restrict__ pqu, unsigned* __restrict__ hdr,
    float* __restrict__ out)
{
    __shared__ float s_red[16][17];
    const int j    = blockIdx.x;    // 0..63
    const int t    = threadIdx.x;   // 0..255
    const int wave = t >> 6;
    const int lane = t & 63;

    // ---- phase 1: reduce part over blocks for slice (c = j>>4, 16 h's) ----
    {
        const int c  = j >> 4;
        const int h0 = (j & 15) * 16;
        const int hh = t & 15;      // h offset within slice
        const int b0 = t >> 4;      // 16 b-phases
        float s = 0.f;
        #pragma unroll 8
        for (int b = b0; b < NBLK; b += 16)
            s += part[((size_t)b * 4 + c) * H + h0 + hh];   // 64B granules
        s_red[b0][hh] = s;
        __syncthreads();
        if (t < 16) {
            float acc = 0.f;
            #pragma unroll
            for (int k = 0; k < 16; ++k) acc += s_red[k][t];
            __hip_atomic_store(&v[c * H + h0 + t], acc,
                               __ATOMIC_RELAXED, __HIP_MEMORY_SCOPE_AGENT);
        }
    }
    __threadfence();
    __syncthreads();
    if (t == 0)
        __hip_atomic_fetch_add(&hdr[0], 1u,
                               __ATOMIC_RELEASE, __HIP_MEMORY_SCOPE_AGENT);
    if (t == 0) {
        while (__hip_atomic_load(&hdr[0], __ATOMIC_ACQUIRE,
                                 __HIP_MEMORY_SCOPE_AGENT) < NMID)
            __builtin_amdgcn_s_sleep(1);
    }
    __syncthreads();

    // ---- phase 2: mid GEMV; wave handles output row h = 4j + wave ----
    const int h = j * 4 + wave;
    {
        float p = 0.f, q = 0.f, u = 0.f;
        #pragma unroll
        for (int i = 0; i < H; i += 64) {
            const int k = i + lane;
            const float v1 = __hip_atomic_load(&v[k],         __ATOMIC_RELAXED, __HIP_MEMORY_SCOPE_AGENT);
            const float v2 = __hip_atomic_load(&v[H + k],     __ATOMIC_RELAXED, __HIP_MEMORY_SCOPE_AGENT);
            const float v3 = __hip_atomic_load(&v[2 * H + k], __ATOMIC_RELAXED, __HIP_MEMORY_SCOPE_AGENT);
            const float v4 = __hip_atomic_load(&v[3 * H + k], __ATOMIC_RELAXED, __HIP_MEMORY_SCOPE_AGENT);
            const float wtu = Wtu[h * H + k];
            const float wtl = Wtl[h * H + k];
            p = fmaf(wtu, v1, fmaf(wtl, v2, p));
            q = fmaf(wtu, v3, fmaf(wtl, v4, q));
            u = fmaf(Wih[h * H + k], hx[k], u);
        }
        #pragma unroll
        for (int off = 32; off > 0; off >>= 1) {
            p += __shfl_down(p, off, 64);
            q += __shfl_down(q, off, 64);
            u += __shfl_down(u, off, 64);
        }
        if (lane == 0) {
            __hip_atomic_store(&pqu[h],         p, __ATOMIC_RELAXED, __HIP_MEMORY_SCOPE_AGENT);
            __hip_atomic_store(&pqu[H + h],     q, __ATOMIC_RELAXED, __HIP_MEMORY_SCOPE_AGENT);
            __hip_atomic_store(&pqu[2 * H + h], u, __ATOMIC_RELAXED, __HIP_MEMORY_SCOPE_AGENT);
        }
    }
    __threadfence();
    __syncthreads();
    if (t == 0)
        __hip_atomic_fetch_add(&hdr[32], 1u,
                               __ATOMIC_RELEASE, __HIP_MEMORY_SCOPE_AGENT);
    if (t == 0) {
        while (__hip_atomic_load(&hdr[32], __ATOMIC_ACQUIRE,
                                 __HIP_MEMORY_SCOPE_AGENT) < NMID)
            __builtin_amdgcn_s_sleep(1);
    }
    __syncthreads();

    // ---- phase 3: out GEMV + sigmoid for row h ----
    {
        float s = 0.f;
        #pragma unroll
        for (int i = 0; i < H; i += 64) {
            const int k = i + lane;
            const float pk = __hip_atomic_load(&pqu[k],     __ATOMIC_RELAXED, __HIP_MEMORY_SCOPE_AGENT);
            const float qk = __hip_atomic_load(&pqu[H + k], __ATOMIC_RELAXED, __HIP_MEMORY_SCOPE_AGENT);
            s = fmaf(Wsu[h * H + k], pk, fmaf(Wsl[h * H + k], qk, s));
        }
        #pragma unroll
        for (int off = 32; off > 0; off >>= 1)
            s += __shfl_down(s, off, 64);
        if (lane == 0) {
            const float u = __hip_atomic_load(&pqu[2 * H + h], __ATOMIC_RELAXED, __HIP_MEMORY_SCOPE_AGENT);
            out[h] = 1.f / (1.f + expf(-(s + u)));
        }
    }
}

extern "C" void kernel_launch(void* const* d_in, const int* in_sizes, int n_in,
                              void* d_out, int out_size, void* d_ws, size_t ws_size,
                              hipStream_t stream) {
    const float* td_u  = (const float*)d_in[0];
    const float* td_l  = (const float*)d_in[1];
    const float* ld_u  = (const float*)d_in[2];
    const float* ld_l  = (const float*)d_in[3];
    const int*   loc   = (const int*)d_in[4];
    const float* hx    = (const float*)d_in[5];
    const float* Wih   = (const float*)d_in[6];
    const float* Wtu   = (const float*)d_in[7];
    const float* Wtl   = (const float*)d_in[8];
    const float* Wsu   = (const float*)d_in[9];
    const float* Wsl   = (const float*)d_in[10];
    const float* table = (const float*)d_in[11];
    const int L = in_sizes[0];

    float*    ws   = (float*)d_ws;
    unsigned* hdr  = (unsigned*)ws;        // counters at byte 0 and 128
    float*    v    = ws + 64;              // 4*H
    float*    pqu  = ws + 64 + 4 * H;      // 3*H
    float*    part = ws + 2048;            // NBLK*4*H (2 MB), 16B-aligned

    strnn_gather<<<NBLK, 256, 0, stream>>>(
        td_u, td_l, ld_u, ld_l, loc, table, hdr, part, L);
    strnn_midout<<<NMID, 256, 0, stream>>>(
        Wtu, Wtl, Wih, Wsu, Wsl, hx, part, v, pqu, hdr, (float*)d_out);
}